// Round 5
// baseline (589.961 us; speedup 1.0000x reference)
//
#include <hip/hip_runtime.h>

// B=16, C=512, H=W=64 -> N=4096, HEADS=8, d=64. fp32 in/out.
// Pipeline:
//   xT = f16(x^T)                                    [b][n][c]
//   qkv_fused: one dispatch, two block flavors:
//     q-blocks : GEMM(wq, xT) + exp + fused softmax-over-d normalize -> eqT
//     kv-blocks: GEMM(wkv head, xT strip) -> ek/v in LDS only (swizzled,
//                aliased over staging); ctx += ek.v^T, rowsum += sum ek
//                (register-accumulated, atomicAdd to 2MB ctxa)
//   ctxm: ctxn = ctx/rowsum; M = wp_h @ ctxn^T
//   GEMM-2: y = x + M[b] @ eqT[b]^T
// GEMM loops: 2-barrier single-buffer, BK=64 (halves the vmcnt(0)-drain count
// vs BK=32; LDS stays 32KB in qkv via full ekvv aliasing). LDS tiles are
// XOR-swizzled via pre-swizzled GLOBAL source + linear global_load_lds dest +
// swizzled fragment read (m201 pattern) to keep ds_read_b128 conflict-free at
// the 128B row stride.

#define NFULL 4096L
#define XTN   2097152L   // 4096*512 per-batch f16 elems
#define CTXS  4160L      // per (b,h): 64*64 ctx + 64 rowsum floats

typedef _Float16 half8 __attribute__((ext_vector_type(8)));
typedef _Float16 half4 __attribute__((ext_vector_type(4)));
typedef float floatx4 __attribute__((ext_vector_type(4)));

__device__ inline void async_copy16(const _Float16* g, _Float16* l) {
  __builtin_amdgcn_global_load_lds(
      (const __attribute__((address_space(1))) void*)g,
      (__attribute__((address_space(3))) void*)l,
      16, 0, 0);
}

// ---------------- f32 -> f16 weight conversion (w_proj) -------------------------
__global__ __launch_bounds__(256) void convert_w_kernel(
    const float* __restrict__ src, _Float16* __restrict__ dst, int n4)
{
  const int i = blockIdx.x * 256 + threadIdx.x;
  if (i < n4) {
    float4 v = reinterpret_cast<const float4*>(src)[i];
    half4 h = {(_Float16)v.x, (_Float16)v.y, (_Float16)v.z, (_Float16)v.w};
    reinterpret_cast<half4*>(dst)[i] = h;
  }
}

// ---------------- w_qkv convert + head-aligned permutation ----------------------
__global__ __launch_bounds__(256) void convert_wqkv_kernel(
    const float* __restrict__ src, _Float16* __restrict__ wq,
    _Float16* __restrict__ wkv)
{
  const int i = blockIdx.x * 256 + threadIdx.x;   // exactly 1536*128 float4s
  const int row = i >> 7, c4 = i & 127;
  const int h = row / 192, r = row - h * 192;
  const int which = r >> 6, ii = r & 63;
  float4 v = reinterpret_cast<const float4*>(src)[i];
  half4 hv = {(_Float16)v.x, (_Float16)v.y, (_Float16)v.z, (_Float16)v.w};
  if (which == 0)
    reinterpret_cast<half4*>(wq)[(h * 64 + ii) * 128 + c4] = hv;
  else
    reinterpret_cast<half4*>(wkv)[(h * 128 + (which - 1) * 64 + ii) * 128 + c4] = hv;
}

// ---------------- x[b][c][n] fp32 -> xT[b][n][c] f16 ----------------------------
__global__ __launch_bounds__(256) void transpose_x_kernel(
    const float* __restrict__ x, _Float16* __restrict__ xT)
{
  __shared__ _Float16 tile[64][68];
  const int bb = blockIdx.z, c0 = blockIdx.y * 64, n0 = blockIdx.x * 64;
  const int t = threadIdx.x;
  const int rr0 = t >> 4;
  const int col4 = (t & 15) * 4;
  const float* xb = x + (long)bb * XTN;
#pragma unroll
  for (int p = 0; p < 4; ++p) {
    const int row = p * 16 + rr0;
    float4 v = *reinterpret_cast<const float4*>(&xb[(long)(c0 + row) * NFULL + n0 + col4]);
    tile[col4 + 0][row] = (_Float16)v.x;
    tile[col4 + 1][row] = (_Float16)v.y;
    tile[col4 + 2][row] = (_Float16)v.z;
    tile[col4 + 3][row] = (_Float16)v.w;
  }
  __syncthreads();
  _Float16* xTb = xT + (long)bb * XTN;
#pragma unroll
  for (int p = 0; p < 4; ++p) {
    const int nrow = p * 16 + rr0;
    half4 h = *reinterpret_cast<const half4*>(&tile[nrow][col4]);
    *reinterpret_cast<half4*>(&xTb[(long)(n0 + nrow) * 512 + c0 + col4]) = h;
  }
}

// ---------------- fused QKV: q-blocks + kv/ctx-blocks in one dispatch -----------
// idx < 128 : q    (by = idx>>5 in 0..3 -> o0, nx = idx&31 -> n0)
// idx >= 128: kv   (j = idx-128; h = j>>4; strip = j&15; 2 n-subtiles of 128)
__global__ __launch_bounds__(256) void qkv_fused_kernel(
    const _Float16* __restrict__ Aq,   // 512 x 512 (permuted wq)
    const _Float16* __restrict__ Akv,  // 1024 x 512 (permuted wkv)
    const _Float16* __restrict__ xT,   // [b][n][512]
    _Float16* __restrict__ eqT,        // [b][n][512] normalized exp(q)
    float* __restrict__ ctxa)
{
  __shared__ __align__(16) _Float16 smem[16384];   // 32KB: As 16K + Bs 16K (ekvv alias)
  const int idx = blockIdx.x, bb = blockIdx.y;
  const _Float16* Bb = xT + (long)bb * XTN;
  const int t = threadIdx.x;
  const int wave = t >> 6, lane = t & 63;
  const int wm = (wave >> 1) * 64, wn = (wave & 1) * 64;
  const int lm = lane & 15, lq = lane >> 4;
  const int lr8 = lane >> 3;                        // row within an 8-row segment
  const int lk8s = ((lane & 7) ^ lr8) * 8;          // pre-swizzled source column
  _Float16* As = smem;
  _Float16* Bs = smem + 8192;

  if (idx < 128) {
    // ---------------- q path ----------------
    const int by = idx >> 5, nx = idx & 31;
    const int o0 = by * 128, n0 = nx * 128;

    floatx4 acc[4][4];
#pragma unroll
    for (int mi = 0; mi < 4; ++mi)
#pragma unroll
      for (int ni = 0; ni < 4; ++ni)
        acc[mi][ni] = (floatx4){0.f, 0.f, 0.f, 0.f};

    for (int k0 = 0; k0 < 512; k0 += 64) {
      __syncthreads();
#pragma unroll
      for (int q = 0; q < 4; ++q) {
        const int seg = wave * 4 + q;
        const int r = seg * 8 + lr8;
        async_copy16(&Aq[(long)(o0 + r) * 512 + k0 + lk8s], &As[seg * 512]);
        async_copy16(&Bb[(long)(n0 + r) * 512 + k0 + lk8s], &Bs[seg * 512]);
      }
      __syncthreads();
#pragma unroll
      for (int kk = 0; kk < 2; ++kk) {
        const int gsw = ((kk * 4 + lq) ^ (lm & 7)) * 8;   // swizzled read group
        half8 af[4], bf[4];
#pragma unroll
        for (int mi = 0; mi < 4; ++mi)
          af[mi] = *reinterpret_cast<const half8*>(&As[(wm + mi * 16 + lm) * 64 + gsw]);
#pragma unroll
        for (int ni = 0; ni < 4; ++ni)
          bf[ni] = *reinterpret_cast<const half8*>(&Bs[(wn + ni * 16 + lm) * 64 + gsw]);
#pragma unroll
        for (int mi = 0; mi < 4; ++mi)
#pragma unroll
          for (int ni = 0; ni < 4; ++ni)
            acc[mi][ni] = __builtin_amdgcn_mfma_f32_16x16x32_f16(af[mi], bf[ni], acc[mi][ni], 0, 0, 0);
      }
    }

    // epilogue: exp -> per-(head, n) colsum over the wave's 64 rows -> normalize
#pragma unroll
    for (int mi = 0; mi < 4; ++mi)
#pragma unroll
      for (int ni = 0; ni < 4; ++ni)
#pragma unroll
        for (int reg = 0; reg < 4; ++reg)
          acc[mi][ni][reg] = __expf(acc[mi][ni][reg]);

    float inv[4];
#pragma unroll
    for (int ni = 0; ni < 4; ++ni) {
      float s = 0.f;
#pragma unroll
      for (int mi = 0; mi < 4; ++mi)
#pragma unroll
        for (int reg = 0; reg < 4; ++reg)
          s += acc[mi][ni][reg];
      s += __shfl_xor(s, 16, 64);
      s += __shfl_xor(s, 32, 64);
      inv[ni] = 1.0f / s;
    }

    const int hh = by * 2 + (wave >> 1);
#pragma unroll
    for (int mi = 0; mi < 4; ++mi) {
      const int i0 = mi * 16 + lq * 4;
#pragma unroll
      for (int ni = 0; ni < 4; ++ni) {
        const long n = n0 + wn + ni * 16 + lm;
        half4 st;
#pragma unroll
        for (int reg = 0; reg < 4; ++reg)
          st[reg] = (_Float16)(acc[mi][ni][reg] * inv[ni]);
        *reinterpret_cast<half4*>(&eqT[((long)bb * NFULL + n) * 512 + hh * 64 + i0]) = st;
      }
    }
  } else {
    // ---------------- kv path ----------------
    const int j = idx - 128;
    const int h = j >> 4, strip = j & 15;
    const _Float16* Ab = Akv + (long)h * 128 * 512;
    const int i0 = (wave >> 1) * 32, j0 = (wave & 1) * 32;  // ctx quadrant per wave
    char* sm = (char*)smem;

    floatx4 ctxacc[2][2];
    floatx4 rsacc[2];
#pragma unroll
    for (int a = 0; a < 2; ++a) {
      rsacc[a] = (floatx4){0.f, 0.f, 0.f, 0.f};
#pragma unroll
      for (int c = 0; c < 2; ++c) ctxacc[a][c] = (floatx4){0.f, 0.f, 0.f, 0.f};
    }
    const half8 ones = {(_Float16)1.f, (_Float16)1.f, (_Float16)1.f, (_Float16)1.f,
                        (_Float16)1.f, (_Float16)1.f, (_Float16)1.f, (_Float16)1.f};

    for (int ns = 0; ns < 2; ++ns) {
      const int n0 = strip * 256 + ns * 128;
      floatx4 acc[4][4];   // acc[ni][mi]: D rows = n, cols = o (swapped mfma)
#pragma unroll
      for (int ni = 0; ni < 4; ++ni)
#pragma unroll
        for (int mi = 0; mi < 4; ++mi)
          acc[ni][mi] = (floatx4){0.f, 0.f, 0.f, 0.f};

      for (int k0 = 0; k0 < 512; k0 += 64) {
        __syncthreads();   // prior ctx-phase / fragment reads of smem done
#pragma unroll
        for (int q = 0; q < 4; ++q) {
          const int seg = wave * 4 + q;
          const int r = seg * 8 + lr8;
          async_copy16(&Ab[(long)r * 512 + k0 + lk8s], &As[seg * 512]);
          async_copy16(&Bb[(long)(n0 + r) * 512 + k0 + lk8s], &Bs[seg * 512]);
        }
        __syncthreads();
#pragma unroll
        for (int kk = 0; kk < 2; ++kk) {
          const int gsw = ((kk * 4 + lq) ^ (lm & 7)) * 8;
          half8 af[4], bf[4];
#pragma unroll
          for (int mi = 0; mi < 4; ++mi)
            af[mi] = *reinterpret_cast<const half8*>(&As[(wm + mi * 16 + lm) * 64 + gsw]);
#pragma unroll
          for (int ni = 0; ni < 4; ++ni)
            bf[ni] = *reinterpret_cast<const half8*>(&Bs[(wn + ni * 16 + lm) * 64 + gsw]);
#pragma unroll
          for (int ni = 0; ni < 4; ++ni)
#pragma unroll
            for (int mi = 0; mi < 4; ++mi)
              acc[ni][mi] = __builtin_amdgcn_mfma_f32_16x16x32_f16(bf[ni], af[mi], acc[ni][mi], 0, 0, 0);
        }
      }
      __syncthreads();   // all waves' fragment reads done before ekvv overwrite

      // scatter D[n][o] into ekvv[o][n-local], XOR-swizzled; exp on ek half (o<64)
      const bool isek = (wm == 0);
#pragma unroll
      for (int ni = 0; ni < 4; ++ni) {
        const int nloc = wn + ni * 16 + lq * 4;
#pragma unroll
        for (int mi = 0; mi < 4; ++mi) {
          const int oc = wm + mi * 16 + lm;
          half4 st;
#pragma unroll
          for (int reg = 0; reg < 4; ++reg) {
            float v = acc[ni][mi][reg];
            if (isek) v = __expf(v);
            st[reg] = (_Float16)v;
          }
          *reinterpret_cast<half4*>(sm + oc * 256 + ((nloc * 2) ^ ((oc & 7) << 4))) = st;
        }
      }
      __syncthreads();

      // ctx[i][j] += sum_n ek[i][n]*vv[j][n]; rowsum[i] += sum_n ek[i][n]
#pragma unroll
      for (int kk = 0; kk < 4; ++kk) {
        const int colb = kk * 64 + lq * 16;
        half8 a2[2], b2[2];
#pragma unroll
        for (int mi = 0; mi < 2; ++mi) {
          const int row = i0 + mi * 16 + lm;
          a2[mi] = *reinterpret_cast<const half8*>(sm + row * 256 + (colb ^ ((row & 7) << 4)));
        }
#pragma unroll
        for (int nj = 0; nj < 2; ++nj) {
          const int row = 64 + j0 + nj * 16 + lm;
          b2[nj] = *reinterpret_cast<const half8*>(sm + row * 256 + (colb ^ ((row & 7) << 4)));
        }
#pragma unroll
        for (int mi = 0; mi < 2; ++mi)
#pragma unroll
          for (int nj = 0; nj < 2; ++nj)
            ctxacc[mi][nj] = __builtin_amdgcn_mfma_f32_16x16x32_f16(a2[mi], b2[nj], ctxacc[mi][nj], 0, 0, 0);
        if (j0 == 0) {
#pragma unroll
          for (int mi = 0; mi < 2; ++mi)
            rsacc[mi] = __builtin_amdgcn_mfma_f32_16x16x32_f16(a2[mi], ones, rsacc[mi], 0, 0, 0);
        }
      }
    }

    float* cp = ctxa + ((long)(bb * 8 + h)) * CTXS;
#pragma unroll
    for (int mi = 0; mi < 2; ++mi)
#pragma unroll
      for (int nj = 0; nj < 2; ++nj)
#pragma unroll
        for (int reg = 0; reg < 4; ++reg)
          atomicAdd(&cp[(i0 + mi * 16 + lq * 4 + reg) * 64 + j0 + nj * 16 + lm],
                    ctxacc[mi][nj][reg]);
    if (j0 == 0 && lm == 0) {
#pragma unroll
      for (int mi = 0; mi < 2; ++mi)
#pragma unroll
        for (int reg = 0; reg < 4; ++reg)
          atomicAdd(&cp[4096 + i0 + mi * 16 + lq * 4 + reg], rsacc[mi][reg]);
    }
  }
}

// ---------------- normalize ctx, M = wp_h @ ctxn^T ------------------------------
__global__ __launch_bounds__(256) void ctxm_kernel(
    const float* __restrict__ ctxa, const _Float16* __restrict__ wp,
    _Float16* __restrict__ M)
{
  __shared__ float rs[64];
  __shared__ _Float16 ctxh[64][72];
  const int h = blockIdx.x, bb = blockIdx.y;
  const int t = threadIdx.x, wave = t >> 6, lane = t & 63;
  const int lm = lane & 15, lq = lane >> 4;
  const float* cp = ctxa + ((long)(bb * 8 + h)) * CTXS;
  if (t < 64) rs[t] = 1.0f / cp[4096 + t];
  __syncthreads();
  for (int e = t; e < 4096; e += 256)
    ctxh[e >> 6][e & 63] = (_Float16)(cp[e] * rs[e >> 6]);
  __syncthreads();

  const _Float16* wpb = wp + h * 64;
  const int o0w = wave * 128;
  floatx4 acc[8][4];
#pragma unroll
  for (int mi = 0; mi < 8; ++mi)
#pragma unroll
    for (int ni = 0; ni < 4; ++ni)
      acc[mi][ni] = (floatx4){0.f, 0.f, 0.f, 0.f};
#pragma unroll
  for (int ks = 0; ks < 2; ++ks) {
    const int jj0 = ks * 32 + lq * 8;
    half8 bfr[4];
#pragma unroll
    for (int ni = 0; ni < 4; ++ni)
      bfr[ni] = *reinterpret_cast<const half8*>(&ctxh[ni * 16 + lm][jj0]);
#pragma unroll
    for (int mi = 0; mi < 8; ++mi) {
      half8 afr = *reinterpret_cast<const half8*>(&wpb[(long)(o0w + mi * 16 + lm) * 512 + jj0]);
#pragma unroll
      for (int ni = 0; ni < 4; ++ni)
        acc[mi][ni] = __builtin_amdgcn_mfma_f32_16x16x32_f16(afr, bfr[ni], acc[mi][ni], 0, 0, 0);
    }
  }
  _Float16* Mb = M + (long)bb * 512 * 512;
#pragma unroll
  for (int mi = 0; mi < 8; ++mi)
#pragma unroll
    for (int reg = 0; reg < 4; ++reg) {
      const int o = o0w + mi * 16 + lq * 4 + reg;
#pragma unroll
      for (int ni = 0; ni < 4; ++ni)
        Mb[(long)o * 512 + h * 64 + ni * 16 + lm] = (_Float16)acc[mi][ni][reg];
    }
}

// ---------------- GEMM-2: y = x + M[b] @ eqT[b]^T -------------------------------
__global__ __launch_bounds__(256) void gemm2_kernel(
    const _Float16* __restrict__ M, const _Float16* __restrict__ eqT,
    const float* __restrict__ x, float* __restrict__ y)
{
  __shared__ __align__(16) _Float16 As[128 * 64];
  __shared__ __align__(16) _Float16 Bs[128 * 64];
  const int bb = blockIdx.z;
  const int o0 = blockIdx.y * 128;
  const int n0 = blockIdx.x * 128;
  const _Float16* Ab = M + (long)bb * 512 * 512;
  const _Float16* Bb = eqT + (long)bb * XTN;
  const int t = threadIdx.x;
  const int wave = t >> 6, lane = t & 63;
  const int wm = (wave >> 1) * 64, wn = (wave & 1) * 64;
  const int lm = lane & 15, lq = lane >> 4;
  const int lr8 = lane >> 3;
  const int lk8s = ((lane & 7) ^ lr8) * 8;

  floatx4 acc[4][4];
#pragma unroll
  for (int mi = 0; mi < 4; ++mi)
#pragma unroll
    for (int ni = 0; ni < 4; ++ni)
      acc[mi][ni] = (floatx4){0.f, 0.f, 0.f, 0.f};

  for (int k0 = 0; k0 < 512; k0 += 64) {
    __syncthreads();
#pragma unroll
    for (int q = 0; q < 4; ++q) {
      const int seg = wave * 4 + q;
      const int r = seg * 8 + lr8;
      async_copy16(&Ab[(long)(o0 + r) * 512 + k0 + lk8s], &As[seg * 512]);
      async_copy16(&Bb[(long)(n0 + r) * 512 + k0 + lk8s], &Bs[seg * 512]);
    }
    __syncthreads();
#pragma unroll
    for (int kk = 0; kk < 2; ++kk) {
      const int gsw = ((kk * 4 + lq) ^ (lm & 7)) * 8;
      half8 af[4], bf[4];
#pragma unroll
      for (int mi = 0; mi < 4; ++mi)
        af[mi] = *reinterpret_cast<const half8*>(&As[(wm + mi * 16 + lm) * 64 + gsw]);
#pragma unroll
      for (int ni = 0; ni < 4; ++ni)
        bf[ni] = *reinterpret_cast<const half8*>(&Bs[(wn + ni * 16 + lm) * 64 + gsw]);
#pragma unroll
      for (int mi = 0; mi < 4; ++mi)
#pragma unroll
        for (int ni = 0; ni < 4; ++ni)
          acc[mi][ni] = __builtin_amdgcn_mfma_f32_16x16x32_f16(af[mi], bf[ni], acc[mi][ni], 0, 0, 0);
    }
  }

  const float* Rb = x + (long)bb * XTN;
  float* Cb = y + (long)bb * XTN;
#pragma unroll
  for (int mi = 0; mi < 4; ++mi)
#pragma unroll
    for (int reg = 0; reg < 4; ++reg) {
      const long orow = o0 + wm + mi * 16 + lq * 4 + reg;
#pragma unroll
      for (int ni = 0; ni < 4; ++ni) {
        const long off = orow * NFULL + n0 + wn + ni * 16 + lm;
        Cb[off] = acc[mi][ni][reg] + Rb[off];
      }
    }
}

extern "C" void kernel_launch(void* const* d_in, const int* in_sizes, int n_in,
                              void* d_out, int out_size, void* d_ws, size_t ws_size,
                              hipStream_t stream)
{
  const float* x      = (const float*)d_in[0];
  const float* w_qkv  = (const float*)d_in[1];
  const float* w_proj = (const float*)d_in[2];
  float* out = (float*)d_out;

  const long WP = 512L * 512;
  char* p = (char*)d_ws;
  _Float16* wqh  = (_Float16*)p; p += 512L * 512 * 2;
  _Float16* wkvh = (_Float16*)p; p += 1024L * 512 * 2;
  _Float16* wph  = (_Float16*)p; p += 512L * 512 * 2;
  _Float16* xT   = (_Float16*)p; p += 16L * XTN * 2;
  _Float16* eqT  = (_Float16*)p; p += 16L * XTN * 2;
  float* ctxa    = (float*)p;    p += 16L * 8 * CTXS * 4;
  _Float16* M    = (_Float16*)p;

  convert_wqkv_kernel<<<dim3(768), 256, 0, stream>>>(w_qkv, wqh, wkvh);
  convert_w_kernel<<<dim3((int)((WP / 4 + 255) / 256)), 256, 0, stream>>>(w_proj, wph, (int)(WP / 4));
  hipMemsetAsync(ctxa, 0, 16L * 8 * CTXS * 4, stream);
  transpose_x_kernel<<<dim3(64, 8, 16), 256, 0, stream>>>(x, xT);
  qkv_fused_kernel<<<dim3(256, 16), 256, 0, stream>>>(wqh, wkvh, xT, eqT, ctxa);
  ctxm_kernel<<<dim3(8, 16), 256, 0, stream>>>(ctxa, wph, M);
  gemm2_kernel<<<dim3(32, 4, 16), 256, 0, stream>>>(M, eqT, x, out);
}

// Round 7
// 500.870 us; speedup vs baseline: 1.1779x; 1.1779x over previous
//
#include <hip/hip_runtime.h>

// B=16, C=512, H=W=64 -> N=4096, HEADS=8, d=64. fp32 in/out.
// Pipeline (round-4 proven core + per-flavor XCD-aware block swizzle):
//   xT = f16(x^T); qkv_fused (q: GEMM+softmax_d -> eqT | kv: GEMM -> ek/v in LDS,
//   ctx reg-accum -> atomicAdd ctxa); ctxm: M = wp_h @ (ctx/rowsum)^T;
//   gemm2: y = x + M @ eqT^T.
// All MFMA GEMM loops: 2-barrier single-buffer BK=32 (1-barrier dbuf, BK=64,
// and 256^2 variants all measured slower or unsafe in this harness).

#define NFULL 4096L
#define XTN   2097152L   // 4096*512 per-batch f16 elems
#define CTXS  4160L      // per (b,h): 64*64 ctx + 64 rowsum floats

typedef _Float16 half8 __attribute__((ext_vector_type(8)));
typedef _Float16 half4 __attribute__((ext_vector_type(4)));
typedef float floatx4 __attribute__((ext_vector_type(4)));

__device__ inline void async_copy16(const _Float16* g, _Float16* l) {
  __builtin_amdgcn_global_load_lds(
      (const __attribute__((address_space(1))) void*)g,
      (__attribute__((address_space(3))) void*)l,
      16, 0, 0);
}

// ---------------- f32 -> f16 weight conversion (w_proj) -------------------------
__global__ __launch_bounds__(256) void convert_w_kernel(
    const float* __restrict__ src, _Float16* __restrict__ dst, int n4)
{
  const int i = blockIdx.x * 256 + threadIdx.x;
  if (i < n4) {
    float4 v = reinterpret_cast<const float4*>(src)[i];
    half4 h = {(_Float16)v.x, (_Float16)v.y, (_Float16)v.z, (_Float16)v.w};
    reinterpret_cast<half4*>(dst)[i] = h;
  }
}

// ---------------- w_qkv convert + head-aligned permutation ----------------------
__global__ __launch_bounds__(256) void convert_wqkv_kernel(
    const float* __restrict__ src, _Float16* __restrict__ wq,
    _Float16* __restrict__ wkv)
{
  const int i = blockIdx.x * 256 + threadIdx.x;   // exactly 1536*128 float4s
  const int row = i >> 7, c4 = i & 127;
  const int h = row / 192, r = row - h * 192;
  const int which = r >> 6, ii = r & 63;
  float4 v = reinterpret_cast<const float4*>(src)[i];
  half4 hv = {(_Float16)v.x, (_Float16)v.y, (_Float16)v.z, (_Float16)v.w};
  if (which == 0)
    reinterpret_cast<half4*>(wq)[(h * 64 + ii) * 128 + c4] = hv;
  else
    reinterpret_cast<half4*>(wkv)[(h * 128 + (which - 1) * 64 + ii) * 128 + c4] = hv;
}

// ---------------- x[b][c][n] fp32 -> xT[b][n][c] f16 ----------------------------
__global__ __launch_bounds__(256) void transpose_x_kernel(
    const float* __restrict__ x, _Float16* __restrict__ xT)
{
  __shared__ _Float16 tile[64][68];
  const int bb = blockIdx.z, c0 = blockIdx.y * 64, n0 = blockIdx.x * 64;
  const int t = threadIdx.x;
  const int rr0 = t >> 4;
  const int col4 = (t & 15) * 4;
  const float* xb = x + (long)bb * XTN;
#pragma unroll
  for (int p = 0; p < 4; ++p) {
    const int row = p * 16 + rr0;
    float4 v = *reinterpret_cast<const float4*>(&xb[(long)(c0 + row) * NFULL + n0 + col4]);
    tile[col4 + 0][row] = (_Float16)v.x;
    tile[col4 + 1][row] = (_Float16)v.y;
    tile[col4 + 2][row] = (_Float16)v.z;
    tile[col4 + 3][row] = (_Float16)v.w;
  }
  __syncthreads();
  _Float16* xTb = xT + (long)bb * XTN;
#pragma unroll
  for (int p = 0; p < 4; ++p) {
    const int nrow = p * 16 + rr0;
    half4 h = *reinterpret_cast<const half4*>(&tile[nrow][col4]);
    *reinterpret_cast<half4*>(&xTb[(long)(n0 + nrow) * 512 + c0 + col4]) = h;
  }
}

// ---------------- fused QKV: q-blocks + kv/ctx-blocks in one dispatch -----------
// Per-flavor XCD swizzle: q (raw<128) and kv (raw>=128) each remapped
// (raw&7)*16 + (raw>>3) so every XCD gets a contiguous, panel-sharing chunk
// of BOTH flavors (load-balanced).
__global__ __launch_bounds__(256) void qkv_fused_kernel(
    const _Float16* __restrict__ Aq,   // 512 x 512 (permuted wq)
    const _Float16* __restrict__ Akv,  // 1024 x 512 (permuted wkv)
    const _Float16* __restrict__ xT,   // [b][n][512]
    _Float16* __restrict__ eqT,        // [b][n][512] normalized exp(q)
    float* __restrict__ ctxa)
{
  __shared__ __align__(16) _Float16 smem[16384];   // 32KB: 16KB staging (+16KB ekvv alias)
  const int raw = blockIdx.x, bb = blockIdx.y;
  const int idx = (raw < 128) ? ((raw & 7) * 16 + (raw >> 3))
                              : (128 + (((raw - 128) & 7) * 16 + ((raw - 128) >> 3)));
  const _Float16* Bb = xT + (long)bb * XTN;
  const int t = threadIdx.x;
  const int wave = t >> 6, lane = t & 63;
  const int wm = (wave >> 1) * 64, wn = (wave & 1) * 64;
  const int lr = lane >> 2, lk = (lane & 3) * 8;
  const int lm = lane & 15, lq = lane >> 4;
  _Float16* As = smem;
  _Float16* Bs = smem + 4096;

  if (idx < 128) {
    // ---------------- q path ----------------
    const int by = idx >> 5, nx = idx & 31;
    const int o0 = by * 128, n0 = nx * 128;

    floatx4 acc[4][4];
#pragma unroll
    for (int mi = 0; mi < 4; ++mi)
#pragma unroll
      for (int ni = 0; ni < 4; ++ni)
        acc[mi][ni] = (floatx4){0.f, 0.f, 0.f, 0.f};

    for (int k0 = 0; k0 < 512; k0 += 32) {
      __syncthreads();
#pragma unroll
      for (int q = 0; q < 2; ++q) {
        const int seg = wave * 2 + q;
        const int r = seg * 16 + lr;
        async_copy16(&Aq[(long)(o0 + r) * 512 + k0 + lk], &As[seg * 512]);
        async_copy16(&Bb[(long)(n0 + r) * 512 + k0 + lk], &Bs[seg * 512]);
      }
      __syncthreads();
      half8 af[4], bf[4];
#pragma unroll
      for (int mi = 0; mi < 4; ++mi)
        af[mi] = *reinterpret_cast<const half8*>(&As[(wm + mi * 16 + lm) * 32 + lq * 8]);
#pragma unroll
      for (int ni = 0; ni < 4; ++ni)
        bf[ni] = *reinterpret_cast<const half8*>(&Bs[(wn + ni * 16 + lm) * 32 + lq * 8]);
#pragma unroll
      for (int mi = 0; mi < 4; ++mi)
#pragma unroll
        for (int ni = 0; ni < 4; ++ni)
          acc[mi][ni] = __builtin_amdgcn_mfma_f32_16x16x32_f16(af[mi], bf[ni], acc[mi][ni], 0, 0, 0);
    }

#pragma unroll
    for (int mi = 0; mi < 4; ++mi)
#pragma unroll
      for (int ni = 0; ni < 4; ++ni)
#pragma unroll
        for (int reg = 0; reg < 4; ++reg)
          acc[mi][ni][reg] = __expf(acc[mi][ni][reg]);

    float inv[4];
#pragma unroll
    for (int ni = 0; ni < 4; ++ni) {
      float s = 0.f;
#pragma unroll
      for (int mi = 0; mi < 4; ++mi)
#pragma unroll
        for (int reg = 0; reg < 4; ++reg)
          s += acc[mi][ni][reg];
      s += __shfl_xor(s, 16, 64);
      s += __shfl_xor(s, 32, 64);
      inv[ni] = 1.0f / s;
    }

    const int hh = by * 2 + (wave >> 1);
#pragma unroll
    for (int mi = 0; mi < 4; ++mi) {
      const int i0 = mi * 16 + lq * 4;
#pragma unroll
      for (int ni = 0; ni < 4; ++ni) {
        const long n = n0 + wn + ni * 16 + lm;
        half4 st;
#pragma unroll
        for (int reg = 0; reg < 4; ++reg)
          st[reg] = (_Float16)(acc[mi][ni][reg] * inv[ni]);
        *reinterpret_cast<half4*>(&eqT[((long)bb * NFULL + n) * 512 + hh * 64 + i0]) = st;
      }
    }
  } else {
    // ---------------- kv path ----------------
    const int j = idx - 128;
    const int h = j >> 4, strip = j & 15;
    const _Float16* Ab = Akv + (long)h * 128 * 512;
    const int i0 = (wave >> 1) * 32, j0 = (wave & 1) * 32;
    char* sm = (char*)smem;

    floatx4 ctxacc[2][2];
    floatx4 rsacc[2];
#pragma unroll
    for (int a = 0; a < 2; ++a) {
      rsacc[a] = (floatx4){0.f, 0.f, 0.f, 0.f};
#pragma unroll
      for (int c = 0; c < 2; ++c) ctxacc[a][c] = (floatx4){0.f, 0.f, 0.f, 0.f};
    }
    const half8 ones = {(_Float16)1.f, (_Float16)1.f, (_Float16)1.f, (_Float16)1.f,
                        (_Float16)1.f, (_Float16)1.f, (_Float16)1.f, (_Float16)1.f};

    for (int ns = 0; ns < 2; ++ns) {
      const int n0 = strip * 256 + ns * 128;
      floatx4 acc[4][4];
#pragma unroll
      for (int ni = 0; ni < 4; ++ni)
#pragma unroll
        for (int mi = 0; mi < 4; ++mi)
          acc[ni][mi] = (floatx4){0.f, 0.f, 0.f, 0.f};

      for (int k0 = 0; k0 < 512; k0 += 32) {
        __syncthreads();
#pragma unroll
        for (int q = 0; q < 2; ++q) {
          const int seg = wave * 2 + q;
          const int r = seg * 16 + lr;
          async_copy16(&Ab[(long)r * 512 + k0 + lk], &As[seg * 512]);
          async_copy16(&Bb[(long)(n0 + r) * 512 + k0 + lk], &Bs[seg * 512]);
        }
        __syncthreads();
        half8 af[4], bf[4];
#pragma unroll
        for (int mi = 0; mi < 4; ++mi)
          af[mi] = *reinterpret_cast<const half8*>(&As[(wm + mi * 16 + lm) * 32 + lq * 8]);
#pragma unroll
        for (int ni = 0; ni < 4; ++ni)
          bf[ni] = *reinterpret_cast<const half8*>(&Bs[(wn + ni * 16 + lm) * 32 + lq * 8]);
#pragma unroll
        for (int ni = 0; ni < 4; ++ni)
#pragma unroll
          for (int mi = 0; mi < 4; ++mi)
            acc[ni][mi] = __builtin_amdgcn_mfma_f32_16x16x32_f16(bf[ni], af[mi], acc[ni][mi], 0, 0, 0);
      }
      __syncthreads();

      const bool isek = (wm == 0);
#pragma unroll
      for (int ni = 0; ni < 4; ++ni) {
        const int nloc = wn + ni * 16 + lq * 4;
#pragma unroll
        for (int mi = 0; mi < 4; ++mi) {
          const int oc = wm + mi * 16 + lm;
          half4 st;
#pragma unroll
          for (int reg = 0; reg < 4; ++reg) {
            float v = acc[ni][mi][reg];
            if (isek) v = __expf(v);
            st[reg] = (_Float16)v;
          }
          *reinterpret_cast<half4*>(sm + oc * 256 + ((nloc * 2) ^ ((oc & 7) << 4))) = st;
        }
      }
      __syncthreads();

#pragma unroll
      for (int kk = 0; kk < 4; ++kk) {
        const int colb = kk * 64 + lq * 16;
        half8 a2[2], b2[2];
#pragma unroll
        for (int mi = 0; mi < 2; ++mi) {
          const int row = i0 + mi * 16 + lm;
          a2[mi] = *reinterpret_cast<const half8*>(sm + row * 256 + (colb ^ ((row & 7) << 4)));
        }
#pragma unroll
        for (int nj = 0; nj < 2; ++nj) {
          const int row = 64 + j0 + nj * 16 + lm;
          b2[nj] = *reinterpret_cast<const half8*>(sm + row * 256 + (colb ^ ((row & 7) << 4)));
        }
#pragma unroll
        for (int mi = 0; mi < 2; ++mi)
#pragma unroll
          for (int nj = 0; nj < 2; ++nj)
            ctxacc[mi][nj] = __builtin_amdgcn_mfma_f32_16x16x32_f16(a2[mi], b2[nj], ctxacc[mi][nj], 0, 0, 0);
        if (j0 == 0) {
#pragma unroll
          for (int mi = 0; mi < 2; ++mi)
            rsacc[mi] = __builtin_amdgcn_mfma_f32_16x16x32_f16(a2[mi], ones, rsacc[mi], 0, 0, 0);
        }
      }
    }

    float* cp = ctxa + ((long)(bb * 8 + h)) * CTXS;
#pragma unroll
    for (int mi = 0; mi < 2; ++mi)
#pragma unroll
      for (int nj = 0; nj < 2; ++nj)
#pragma unroll
        for (int reg = 0; reg < 4; ++reg)
          atomicAdd(&cp[(i0 + mi * 16 + lq * 4 + reg) * 64 + j0 + nj * 16 + lm],
                    ctxacc[mi][nj][reg]);
    if (j0 == 0 && lm == 0) {
#pragma unroll
      for (int mi = 0; mi < 2; ++mi)
#pragma unroll
        for (int reg = 0; reg < 4; ++reg)
          atomicAdd(&cp[4096 + i0 + mi * 16 + lq * 4 + reg], rsacc[mi][reg]);
    }
  }
}

// ---------------- normalize ctx, M = wp_h @ ctxn^T ------------------------------
__global__ __launch_bounds__(256) void ctxm_kernel(
    const float* __restrict__ ctxa, const _Float16* __restrict__ wp,
    _Float16* __restrict__ M)
{
  __shared__ float rs[64];
  __shared__ _Float16 ctxh[64][72];
  const int h = blockIdx.x, bb = blockIdx.y;
  const int t = threadIdx.x, wave = t >> 6, lane = t & 63;
  const int lm = lane & 15, lq = lane >> 4;
  const float* cp = ctxa + ((long)(bb * 8 + h)) * CTXS;
  if (t < 64) rs[t] = 1.0f / cp[4096 + t];
  __syncthreads();
  for (int e = t; e < 4096; e += 256)
    ctxh[e >> 6][e & 63] = (_Float16)(cp[e] * rs[e >> 6]);
  __syncthreads();

  const _Float16* wpb = wp + h * 64;
  const int o0w = wave * 128;
  floatx4 acc[8][4];
#pragma unroll
  for (int mi = 0; mi < 8; ++mi)
#pragma unroll
    for (int ni = 0; ni < 4; ++ni)
      acc[mi][ni] = (floatx4){0.f, 0.f, 0.f, 0.f};
#pragma unroll
  for (int ks = 0; ks < 2; ++ks) {
    const int jj0 = ks * 32 + lq * 8;
    half8 bfr[4];
#pragma unroll
    for (int ni = 0; ni < 4; ++ni)
      bfr[ni] = *reinterpret_cast<const half8*>(&ctxh[ni * 16 + lm][jj0]);
#pragma unroll
    for (int mi = 0; mi < 8; ++mi) {
      half8 afr = *reinterpret_cast<const half8*>(&wpb[(long)(o0w + mi * 16 + lm) * 512 + jj0]);
#pragma unroll
      for (int ni = 0; ni < 4; ++ni)
        acc[mi][ni] = __builtin_amdgcn_mfma_f32_16x16x32_f16(afr, bfr[ni], acc[mi][ni], 0, 0, 0);
    }
  }
  _Float16* Mb = M + (long)bb * 512 * 512;
#pragma unroll
  for (int mi = 0; mi < 8; ++mi)
#pragma unroll
    for (int reg = 0; reg < 4; ++reg) {
      const int o = o0w + mi * 16 + lq * 4 + reg;
#pragma unroll
      for (int ni = 0; ni < 4; ++ni)
        Mb[(long)o * 512 + h * 64 + ni * 16 + lm] = (_Float16)acc[mi][ni][reg];
    }
}

// ---------------- GEMM-2: y = x + M[b] @ eqT[b]^T -------------------------------
// XCD swizzle on the 32-wide n dimension (32%8==0, bijective).
__global__ __launch_bounds__(256) void gemm2_kernel(
    const _Float16* __restrict__ M, const _Float16* __restrict__ eqT,
    const float* __restrict__ x, float* __restrict__ y)
{
  __shared__ __align__(16) _Float16 As[128 * 32];
  __shared__ __align__(16) _Float16 Bs[128 * 32];
  const int bb = blockIdx.z;
  const int o0 = blockIdx.y * 128;
  const int rawn = blockIdx.x;
  const int n0 = ((rawn & 7) * 4 + (rawn >> 3)) * 128;
  const _Float16* Ab = M + (long)bb * 512 * 512;
  const _Float16* Bb = eqT + (long)bb * XTN;
  const int t = threadIdx.x;
  const int wave = t >> 6, lane = t & 63;
  const int wm = (wave >> 1) * 64, wn = (wave & 1) * 64;
  const int lr = lane >> 2, lk = (lane & 3) * 8;
  const int lm = lane & 15, lq = lane >> 4;

  floatx4 acc[4][4];
#pragma unroll
  for (int mi = 0; mi < 4; ++mi)
#pragma unroll
    for (int ni = 0; ni < 4; ++ni)
      acc[mi][ni] = (floatx4){0.f, 0.f, 0.f, 0.f};

  for (int k0 = 0; k0 < 512; k0 += 32) {
    __syncthreads();
#pragma unroll
    for (int q = 0; q < 2; ++q) {
      const int seg = wave * 2 + q;
      const int r = seg * 16 + lr;
      async_copy16(&Ab[(long)(o0 + r) * 512 + k0 + lk], &As[seg * 512]);
      async_copy16(&Bb[(long)(n0 + r) * 512 + k0 + lk], &Bs[seg * 512]);
    }
    __syncthreads();
    half8 af[4], bf[4];
#pragma unroll
    for (int mi = 0; mi < 4; ++mi)
      af[mi] = *reinterpret_cast<const half8*>(&As[(wm + mi * 16 + lm) * 32 + lq * 8]);
#pragma unroll
    for (int ni = 0; ni < 4; ++ni)
      bf[ni] = *reinterpret_cast<const half8*>(&Bs[(wn + ni * 16 + lm) * 32 + lq * 8]);
#pragma unroll
    for (int mi = 0; mi < 4; ++mi)
#pragma unroll
      for (int ni = 0; ni < 4; ++ni)
        acc[mi][ni] = __builtin_amdgcn_mfma_f32_16x16x32_f16(af[mi], bf[ni], acc[mi][ni], 0, 0, 0);
  }

  const float* Rb = x + (long)bb * XTN;
  float* Cb = y + (long)bb * XTN;
#pragma unroll
  for (int mi = 0; mi < 4; ++mi)
#pragma unroll
    for (int reg = 0; reg < 4; ++reg) {
      const long orow = o0 + wm + mi * 16 + lq * 4 + reg;
#pragma unroll
      for (int ni = 0; ni < 4; ++ni) {
        const long off = orow * NFULL + n0 + wn + ni * 16 + lm;
        Cb[off] = acc[mi][ni][reg] + Rb[off];
      }
    }
}

extern "C" void kernel_launch(void* const* d_in, const int* in_sizes, int n_in,
                              void* d_out, int out_size, void* d_ws, size_t ws_size,
                              hipStream_t stream)
{
  const float* x      = (const float*)d_in[0];
  const float* w_qkv  = (const float*)d_in[1];
  const float* w_proj = (const float*)d_in[2];
  float* out = (float*)d_out;

  const long WP = 512L * 512;
  char* p = (char*)d_ws;
  _Float16* wqh  = (_Float16*)p; p += 512L * 512 * 2;
  _Float16* wkvh = (_Float16*)p; p += 1024L * 512 * 2;
  _Float16* wph  = (_Float16*)p; p += 512L * 512 * 2;
  _Float16* xT   = (_Float16*)p; p += 16L * XTN * 2;
  _Float16* eqT  = (_Float16*)p; p += 16L * XTN * 2;
  float* ctxa    = (float*)p;    p += 16L * 8 * CTXS * 4;
  _Float16* M    = (_Float16*)p;

  convert_wqkv_kernel<<<dim3(768), 256, 0, stream>>>(w_qkv, wqh, wkvh);
  convert_w_kernel<<<dim3((int)((WP / 4 + 255) / 256)), 256, 0, stream>>>(w_proj, wph, (int)(WP / 4));
  hipMemsetAsync(ctxa, 0, 16L * 8 * CTXS * 4, stream);
  transpose_x_kernel<<<dim3(64, 8, 16), 256, 0, stream>>>(x, xT);
  qkv_fused_kernel<<<dim3(256, 16), 256, 0, stream>>>(wqh, wkvh, xT, eqT, ctxa);
  ctxm_kernel<<<dim3(8, 16), 256, 0, stream>>>(ctxa, wph, M);
  gemm2_kernel<<<dim3(32, 4, 16), 256, 0, stream>>>(M, eqT, x, out);
}

// Round 8
// 473.206 us; speedup vs baseline: 1.2467x; 1.0585x over previous
//
#include <hip/hip_runtime.h>

// B=16, C=512, H=W=64 -> N=4096, HEADS=8, d=64. fp32 in/out.
// Pipeline (round-4 core, no XCD swizzle):
//   xT = f16(x^T)  [128x128-tile transpose, wide contiguous segments]
//   qkv_fused: q-blocks (GEMM+softmax_d -> eqT) + kv-blocks (GEMM -> ek/v in
//     LDS (swizzled, aliased over staging); ctx reg-accum -> atomicAdd ctxa),
//     ONE 128-n subtile per kv block for q/kv load balance (grid 384/bb).
//   ctxm: M = wp_h @ (ctx/rowsum)^T;  gemm2: y = x + M @ eqT^T.
// All MFMA GEMM loops: 2-barrier single-buffer BK=32 (dbuf/BK64/256^2/XCD-swz
// all measured slower or unsafe in this harness).

#define NFULL 4096L
#define XTN   2097152L   // 4096*512 per-batch elems
#define CTXS  4160L      // per (b,h): 64*64 ctx + 64 rowsum floats

typedef _Float16 half8 __attribute__((ext_vector_type(8)));
typedef _Float16 half4 __attribute__((ext_vector_type(4)));
typedef float floatx4 __attribute__((ext_vector_type(4)));

__device__ inline void async_copy16(const _Float16* g, _Float16* l) {
  __builtin_amdgcn_global_load_lds(
      (const __attribute__((address_space(1))) void*)g,
      (__attribute__((address_space(3))) void*)l,
      16, 0, 0);
}

// ---------------- f32 -> f16 weight conversion (w_proj) -------------------------
__global__ __launch_bounds__(256) void convert_w_kernel(
    const float* __restrict__ src, _Float16* __restrict__ dst, int n4)
{
  const int i = blockIdx.x * 256 + threadIdx.x;
  if (i < n4) {
    float4 v = reinterpret_cast<const float4*>(src)[i];
    half4 h = {(_Float16)v.x, (_Float16)v.y, (_Float16)v.z, (_Float16)v.w};
    reinterpret_cast<half4*>(dst)[i] = h;
  }
}

// ---------------- w_qkv convert + head-aligned permutation ----------------------
__global__ __launch_bounds__(256) void convert_wqkv_kernel(
    const float* __restrict__ src, _Float16* __restrict__ wq,
    _Float16* __restrict__ wkv)
{
  const int i = blockIdx.x * 256 + threadIdx.x;   // exactly 1536*128 float4s
  const int row = i >> 7, c4 = i & 127;
  const int h = row / 192, r = row - h * 192;
  const int which = r >> 6, ii = r & 63;
  float4 v = reinterpret_cast<const float4*>(src)[i];
  half4 hv = {(_Float16)v.x, (_Float16)v.y, (_Float16)v.z, (_Float16)v.w};
  if (which == 0)
    reinterpret_cast<half4*>(wq)[(h * 64 + ii) * 128 + c4] = hv;
  else
    reinterpret_cast<half4*>(wkv)[(h * 128 + (which - 1) * 64 + ii) * 128 + c4] = hv;
}

// ---------------- x[b][c][n] fp32 -> xT[b][n][c] f16 (128x128 tiles) ------------
// Reads: 512B contiguous per c-row (32 lanes x float4). Writes: 256B contiguous
// per n-row (16 lanes x half8). Transpose happens on the LDS scatter-write.
__global__ __launch_bounds__(256) void transpose_x_kernel(
    const float* __restrict__ x, _Float16* __restrict__ xT)
{
  __shared__ _Float16 tile[128][130];   // [n][c], 33.3 KB
  const int bb = blockIdx.z, c0 = blockIdx.y * 128, n0 = blockIdx.x * 128;
  const int t = threadIdx.x;
  const float* xb = x + (long)bb * XTN;
  const int cl = t >> 5;          // 0..7
  const int nl = (t & 31) * 4;    // 0..124
#pragma unroll
  for (int it = 0; it < 16; ++it) {
    const int c = it * 8 + cl;
    float4 v = *reinterpret_cast<const float4*>(&xb[(long)(c0 + c) * NFULL + n0 + nl]);
    tile[nl + 0][c] = (_Float16)v.x;
    tile[nl + 1][c] = (_Float16)v.y;
    tile[nl + 2][c] = (_Float16)v.z;
    tile[nl + 3][c] = (_Float16)v.w;
  }
  __syncthreads();
  _Float16* xTb = xT + (long)bb * XTN;
  const int nr = t >> 4;          // 0..15
  const int cg = (t & 15) * 8;    // 0..120
#pragma unroll
  for (int it = 0; it < 8; ++it) {
    const int n = it * 16 + nr;
    half8 h = *reinterpret_cast<const half8*>(&tile[n][cg]);
    *reinterpret_cast<half8*>(&xTb[(long)(n0 + n) * 512 + c0 + cg]) = h;
  }
}

// ---------------- fused QKV: q-blocks + kv/ctx-blocks in one dispatch -----------
// idx < 128 : q  (by = idx>>5 -> o0, nx = idx&31 -> n0)
// idx >= 128: kv (j = idx-128 in [0,256); h = j>>5; strip = j&31 -> one 128-n tile)
__global__ __launch_bounds__(256) void qkv_fused_kernel(
    const _Float16* __restrict__ Aq,   // 512 x 512 (permuted wq)
    const _Float16* __restrict__ Akv,  // 1024 x 512 (permuted wkv)
    const _Float16* __restrict__ xT,   // [b][n][512]
    _Float16* __restrict__ eqT,        // [b][n][512] normalized exp(q)
    float* __restrict__ ctxa)
{
  __shared__ __align__(16) _Float16 smem[16384];   // 32KB: 16KB staging (+16KB ekvv alias)
  const int idx = blockIdx.x, bb = blockIdx.y;
  const _Float16* Bb = xT + (long)bb * XTN;
  const int t = threadIdx.x;
  const int wave = t >> 6, lane = t & 63;
  const int wm = (wave >> 1) * 64, wn = (wave & 1) * 64;
  const int lr = lane >> 2, lk = (lane & 3) * 8;
  const int lm = lane & 15, lq = lane >> 4;
  _Float16* As = smem;
  _Float16* Bs = smem + 4096;

  if (idx < 128) {
    // ---------------- q path ----------------
    const int by = idx >> 5, nx = idx & 31;
    const int o0 = by * 128, n0 = nx * 128;

    floatx4 acc[4][4];
#pragma unroll
    for (int mi = 0; mi < 4; ++mi)
#pragma unroll
      for (int ni = 0; ni < 4; ++ni)
        acc[mi][ni] = (floatx4){0.f, 0.f, 0.f, 0.f};

    for (int k0 = 0; k0 < 512; k0 += 32) {
      __syncthreads();
#pragma unroll
      for (int q = 0; q < 2; ++q) {
        const int seg = wave * 2 + q;
        const int r = seg * 16 + lr;
        async_copy16(&Aq[(long)(o0 + r) * 512 + k0 + lk], &As[seg * 512]);
        async_copy16(&Bb[(long)(n0 + r) * 512 + k0 + lk], &Bs[seg * 512]);
      }
      __syncthreads();
      half8 af[4], bf[4];
#pragma unroll
      for (int mi = 0; mi < 4; ++mi)
        af[mi] = *reinterpret_cast<const half8*>(&As[(wm + mi * 16 + lm) * 32 + lq * 8]);
#pragma unroll
      for (int ni = 0; ni < 4; ++ni)
        bf[ni] = *reinterpret_cast<const half8*>(&Bs[(wn + ni * 16 + lm) * 32 + lq * 8]);
#pragma unroll
      for (int mi = 0; mi < 4; ++mi)
#pragma unroll
        for (int ni = 0; ni < 4; ++ni)
          acc[mi][ni] = __builtin_amdgcn_mfma_f32_16x16x32_f16(af[mi], bf[ni], acc[mi][ni], 0, 0, 0);
    }

#pragma unroll
    for (int mi = 0; mi < 4; ++mi)
#pragma unroll
      for (int ni = 0; ni < 4; ++ni)
#pragma unroll
        for (int reg = 0; reg < 4; ++reg)
          acc[mi][ni][reg] = __expf(acc[mi][ni][reg]);

    float inv[4];
#pragma unroll
    for (int ni = 0; ni < 4; ++ni) {
      float s = 0.f;
#pragma unroll
      for (int mi = 0; mi < 4; ++mi)
#pragma unroll
        for (int reg = 0; reg < 4; ++reg)
          s += acc[mi][ni][reg];
      s += __shfl_xor(s, 16, 64);
      s += __shfl_xor(s, 32, 64);
      inv[ni] = 1.0f / s;
    }

    const int hh = by * 2 + (wave >> 1);
#pragma unroll
    for (int mi = 0; mi < 4; ++mi) {
      const int i0 = mi * 16 + lq * 4;
#pragma unroll
      for (int ni = 0; ni < 4; ++ni) {
        const long n = n0 + wn + ni * 16 + lm;
        half4 st;
#pragma unroll
        for (int reg = 0; reg < 4; ++reg)
          st[reg] = (_Float16)(acc[mi][ni][reg] * inv[ni]);
        *reinterpret_cast<half4*>(&eqT[((long)bb * NFULL + n) * 512 + hh * 64 + i0]) = st;
      }
    }
  } else {
    // ---------------- kv path (one 128-n subtile per block) ----------------
    const int j = idx - 128;
    const int h = j >> 5, strip = j & 31;
    const int n0 = strip * 128;
    const _Float16* Ab = Akv + (long)h * 128 * 512;
    const int i0 = (wave >> 1) * 32, j0 = (wave & 1) * 32;
    char* sm = (char*)smem;

    floatx4 ctxacc[2][2];
    floatx4 rsacc[2];
#pragma unroll
    for (int a = 0; a < 2; ++a) {
      rsacc[a] = (floatx4){0.f, 0.f, 0.f, 0.f};
#pragma unroll
      for (int c = 0; c < 2; ++c) ctxacc[a][c] = (floatx4){0.f, 0.f, 0.f, 0.f};
    }
    const half8 ones = {(_Float16)1.f, (_Float16)1.f, (_Float16)1.f, (_Float16)1.f,
                        (_Float16)1.f, (_Float16)1.f, (_Float16)1.f, (_Float16)1.f};

    floatx4 acc[4][4];   // acc[ni][mi]: D rows = n, cols = o (swapped mfma)
#pragma unroll
    for (int ni = 0; ni < 4; ++ni)
#pragma unroll
      for (int mi = 0; mi < 4; ++mi)
        acc[ni][mi] = (floatx4){0.f, 0.f, 0.f, 0.f};

    for (int k0 = 0; k0 < 512; k0 += 32) {
      __syncthreads();
#pragma unroll
      for (int q = 0; q < 2; ++q) {
        const int seg = wave * 2 + q;
        const int r = seg * 16 + lr;
        async_copy16(&Ab[(long)r * 512 + k0 + lk], &As[seg * 512]);
        async_copy16(&Bb[(long)(n0 + r) * 512 + k0 + lk], &Bs[seg * 512]);
      }
      __syncthreads();
      half8 af[4], bf[4];
#pragma unroll
      for (int mi = 0; mi < 4; ++mi)
        af[mi] = *reinterpret_cast<const half8*>(&As[(wm + mi * 16 + lm) * 32 + lq * 8]);
#pragma unroll
      for (int ni = 0; ni < 4; ++ni)
        bf[ni] = *reinterpret_cast<const half8*>(&Bs[(wn + ni * 16 + lm) * 32 + lq * 8]);
#pragma unroll
      for (int ni = 0; ni < 4; ++ni)
#pragma unroll
        for (int mi = 0; mi < 4; ++mi)
          acc[ni][mi] = __builtin_amdgcn_mfma_f32_16x16x32_f16(bf[ni], af[mi], acc[ni][mi], 0, 0, 0);
    }
    __syncthreads();   // all waves' fragment reads done before ekvv overwrite

    // scatter D[n][o] into ekvv[o][n-local], XOR-swizzled; exp on ek half (o<64)
    const bool isek = (wm == 0);
#pragma unroll
    for (int ni = 0; ni < 4; ++ni) {
      const int nloc = wn + ni * 16 + lq * 4;
#pragma unroll
      for (int mi = 0; mi < 4; ++mi) {
        const int oc = wm + mi * 16 + lm;
        half4 st;
#pragma unroll
        for (int reg = 0; reg < 4; ++reg) {
          float v = acc[ni][mi][reg];
          if (isek) v = __expf(v);
          st[reg] = (_Float16)v;
        }
        *reinterpret_cast<half4*>(sm + oc * 256 + ((nloc * 2) ^ ((oc & 7) << 4))) = st;
      }
    }
    __syncthreads();

    // ctx[i][j] += sum_n ek[i][n]*vv[j][n]; rowsum[i] += sum_n ek[i][n]
#pragma unroll
    for (int kk = 0; kk < 4; ++kk) {
      const int colb = kk * 64 + lq * 16;
      half8 a2[2], b2[2];
#pragma unroll
      for (int mi = 0; mi < 2; ++mi) {
        const int row = i0 + mi * 16 + lm;
        a2[mi] = *reinterpret_cast<const half8*>(sm + row * 256 + (colb ^ ((row & 7) << 4)));
      }
#pragma unroll
      for (int nj = 0; nj < 2; ++nj) {
        const int row = 64 + j0 + nj * 16 + lm;
        b2[nj] = *reinterpret_cast<const half8*>(sm + row * 256 + (colb ^ ((row & 7) << 4)));
      }
#pragma unroll
      for (int mi = 0; mi < 2; ++mi)
#pragma unroll
        for (int nj = 0; nj < 2; ++nj)
          ctxacc[mi][nj] = __builtin_amdgcn_mfma_f32_16x16x32_f16(a2[mi], b2[nj], ctxacc[mi][nj], 0, 0, 0);
      if (j0 == 0) {
#pragma unroll
        for (int mi = 0; mi < 2; ++mi)
          rsacc[mi] = __builtin_amdgcn_mfma_f32_16x16x32_f16(a2[mi], ones, rsacc[mi], 0, 0, 0);
      }
    }

    float* cp = ctxa + ((long)(bb * 8 + h)) * CTXS;
#pragma unroll
    for (int mi = 0; mi < 2; ++mi)
#pragma unroll
      for (int nj = 0; nj < 2; ++nj)
#pragma unroll
        for (int reg = 0; reg < 4; ++reg)
          atomicAdd(&cp[(i0 + mi * 16 + lq * 4 + reg) * 64 + j0 + nj * 16 + lm],
                    ctxacc[mi][nj][reg]);
    if (j0 == 0 && lm == 0) {
#pragma unroll
      for (int mi = 0; mi < 2; ++mi)
#pragma unroll
        for (int reg = 0; reg < 4; ++reg)
          atomicAdd(&cp[4096 + i0 + mi * 16 + lq * 4 + reg], rsacc[mi][reg]);
    }
  }
}

// ---------------- normalize ctx, M = wp_h @ ctxn^T ------------------------------
__global__ __launch_bounds__(256) void ctxm_kernel(
    const float* __restrict__ ctxa, const _Float16* __restrict__ wp,
    _Float16* __restrict__ M)
{
  __shared__ float rs[64];
  __shared__ _Float16 ctxh[64][72];
  const int h = blockIdx.x, bb = blockIdx.y;
  const int t = threadIdx.x, wave = t >> 6, lane = t & 63;
  const int lm = lane & 15, lq = lane >> 4;
  const float* cp = ctxa + ((long)(bb * 8 + h)) * CTXS;
  if (t < 64) rs[t] = 1.0f / cp[4096 + t];
  __syncthreads();
  for (int e = t; e < 4096; e += 256)
    ctxh[e >> 6][e & 63] = (_Float16)(cp[e] * rs[e >> 6]);
  __syncthreads();

  const _Float16* wpb = wp + h * 64;
  const int o0w = wave * 128;
  floatx4 acc[8][4];
#pragma unroll
  for (int mi = 0; mi < 8; ++mi)
#pragma unroll
    for (int ni = 0; ni < 4; ++ni)
      acc[mi][ni] = (floatx4){0.f, 0.f, 0.f, 0.f};
#pragma unroll
  for (int ks = 0; ks < 2; ++ks) {
    const int jj0 = ks * 32 + lq * 8;
    half8 bfr[4];
#pragma unroll
    for (int ni = 0; ni < 4; ++ni)
      bfr[ni] = *reinterpret_cast<const half8*>(&ctxh[ni * 16 + lm][jj0]);
#pragma unroll
    for (int mi = 0; mi < 8; ++mi) {
      half8 afr = *reinterpret_cast<const half8*>(&wpb[(long)(o0w + mi * 16 + lm) * 512 + jj0]);
#pragma unroll
      for (int ni = 0; ni < 4; ++ni)
        acc[mi][ni] = __builtin_amdgcn_mfma_f32_16x16x32_f16(afr, bfr[ni], acc[mi][ni], 0, 0, 0);
    }
  }
  _Float16* Mb = M + (long)bb * 512 * 512;
#pragma unroll
  for (int mi = 0; mi < 8; ++mi)
#pragma unroll
    for (int reg = 0; reg < 4; ++reg) {
      const int o = o0w + mi * 16 + lq * 4 + reg;
#pragma unroll
      for (int ni = 0; ni < 4; ++ni)
        Mb[(long)o * 512 + h * 64 + ni * 16 + lm] = (_Float16)acc[mi][ni][reg];
    }
}

// ---------------- GEMM-2: y = x + M[b] @ eqT[b]^T -------------------------------
__global__ __launch_bounds__(256) void gemm2_kernel(
    const _Float16* __restrict__ M, const _Float16* __restrict__ eqT,
    const float* __restrict__ x, float* __restrict__ y)
{
  __shared__ __align__(16) _Float16 As[128 * 32];
  __shared__ __align__(16) _Float16 Bs[128 * 32];
  const int bb = blockIdx.z;
  const int o0 = blockIdx.y * 128;
  const int n0 = blockIdx.x * 128;
  const _Float16* Ab = M + (long)bb * 512 * 512;
  const _Float16* Bb = eqT + (long)bb * XTN;
  const int t = threadIdx.x;
  const int wave = t >> 6, lane = t & 63;
  const int wm = (wave >> 1) * 64, wn = (wave & 1) * 64;
  const int lr = lane >> 2, lk = (lane & 3) * 8;
  const int lm = lane & 15, lq = lane >> 4;

  floatx4 acc[4][4];
#pragma unroll
  for (int mi = 0; mi < 4; ++mi)
#pragma unroll
    for (int ni = 0; ni < 4; ++ni)
      acc[mi][ni] = (floatx4){0.f, 0.f, 0.f, 0.f};

  for (int k0 = 0; k0 < 512; k0 += 32) {
    __syncthreads();
#pragma unroll
    for (int q = 0; q < 2; ++q) {
      const int seg = wave * 2 + q;
      const int r = seg * 16 + lr;
      async_copy16(&Ab[(long)(o0 + r) * 512 + k0 + lk], &As[seg * 512]);
      async_copy16(&Bb[(long)(n0 + r) * 512 + k0 + lk], &Bs[seg * 512]);
    }
    __syncthreads();
    half8 af[4], bf[4];
#pragma unroll
    for (int mi = 0; mi < 4; ++mi)
      af[mi] = *reinterpret_cast<const half8*>(&As[(wm + mi * 16 + lm) * 32 + lq * 8]);
#pragma unroll
    for (int ni = 0; ni < 4; ++ni)
      bf[ni] = *reinterpret_cast<const half8*>(&Bs[(wn + ni * 16 + lm) * 32 + lq * 8]);
#pragma unroll
    for (int mi = 0; mi < 4; ++mi)
#pragma unroll
      for (int ni = 0; ni < 4; ++ni)
        acc[mi][ni] = __builtin_amdgcn_mfma_f32_16x16x32_f16(af[mi], bf[ni], acc[mi][ni], 0, 0, 0);
  }

  const float* Rb = x + (long)bb * XTN;
  float* Cb = y + (long)bb * XTN;
#pragma unroll
  for (int mi = 0; mi < 4; ++mi)
#pragma unroll
    for (int reg = 0; reg < 4; ++reg) {
      const long orow = o0 + wm + mi * 16 + lq * 4 + reg;
#pragma unroll
      for (int ni = 0; ni < 4; ++ni) {
        const long off = orow * NFULL + n0 + wn + ni * 16 + lm;
        Cb[off] = acc[mi][ni][reg] + Rb[off];
      }
    }
}

extern "C" void kernel_launch(void* const* d_in, const int* in_sizes, int n_in,
                              void* d_out, int out_size, void* d_ws, size_t ws_size,
                              hipStream_t stream)
{
  const float* x      = (const float*)d_in[0];
  const float* w_qkv  = (const float*)d_in[1];
  const float* w_proj = (const float*)d_in[2];
  float* out = (float*)d_out;

  const long WP = 512L * 512;
  char* p = (char*)d_ws;
  _Float16* wqh  = (_Float16*)p; p += 512L * 512 * 2;
  _Float16* wkvh = (_Float16*)p; p += 1024L * 512 * 2;
  _Float16* wph  = (_Float16*)p; p += 512L * 512 * 2;
  _Float16* xT   = (_Float16*)p; p += 16L * XTN * 2;
  _Float16* eqT  = (_Float16*)p; p += 16L * XTN * 2;
  float* ctxa    = (float*)p;    p += 16L * 8 * CTXS * 4;
  _Float16* M    = (_Float16*)p;

  convert_wqkv_kernel<<<dim3(768), 256, 0, stream>>>(w_qkv, wqh, wkvh);
  convert_w_kernel<<<dim3((int)((WP / 4 + 255) / 256)), 256, 0, stream>>>(w_proj, wph, (int)(WP / 4));
  hipMemsetAsync(ctxa, 0, 16L * 8 * CTXS * 4, stream);
  transpose_x_kernel<<<dim3(32, 4, 16), 256, 0, stream>>>(x, xT);
  qkv_fused_kernel<<<dim3(384, 16), 256, 0, stream>>>(wqh, wkvh, xT, eqT, ctxa);
  ctxm_kernel<<<dim3(8, 16), 256, 0, stream>>>(ctxa, wph, M);
  gemm2_kernel<<<dim3(32, 4, 16), 256, 0, stream>>>(M, eqT, x, out);
}